// Round 8
// baseline (370.394 us; speedup 1.0000x reference)
//
#include <hip/hip_runtime.h>
#include <hip/hip_bf16.h>

#define N_NODES 50000
#define N_EDGES 800000
#define HIDDEN  256
#define N_LAYERS 3
#define N_PAIRS 4096
#define N_LABEL 8192            // 2*N_PAIRS labeled rows
#define NPAD    50176           // 196*256, padded node count for the scan
#define SCAN_BLOCKS (NPAD / 256) // 196
#define WSZ (HIDDEN * HIDDEN)    // 65536 elems per weight matrix
#define NSTEP (HIDDEN / 32)      // 8 K-steps
#define NBUCKET 196              // dst>>8 buckets (256 nodes each)
#define EDGE_BLOCKS 196          // K1 blocks x 4096 edges = 802816 >= N_EDGES

// Column-blocked x0 layout for the XCD-sliced segment sum:
//   x0b[slice][node][32], slice = col>>5. One slice = 3.2 MB < 4 MB XCD L2.
// Row N_NODES is an all-zero SENTINEL row: CSR segments are padded to a
// multiple of 8 with edges pointing at it -> branch-free window-8 seg loop.
#define NROWPAD (N_NODES + 1)
#define SLICE_ELEMS ((size_t)NROWPAD * 32)
#define SEG_CHUNKS ((N_NODES + 63) / 64)   // 782

typedef __bf16 bf16x8 __attribute__((ext_vector_type(8)));
typedef float  f32x4  __attribute__((ext_vector_type(4)));
typedef float  f32x2  __attribute__((ext_vector_type(2)));

__device__ __forceinline__ void load_lds16(const void* g, void* l) {
    __builtin_amdgcn_global_load_lds(
        (const __attribute__((address_space(1))) void*)g,
        (__attribute__((address_space(3))) void*)l, 16, 0, 0);
}

// accumulate 8 bf16 (as uint4) into 4 packed f32 pairs (v_pk_add_f32 path)
__device__ __forceinline__ void acc8(const uint4 w, f32x2* a) {
    a[0] += (f32x2){__uint_as_float(w.x << 16), __uint_as_float(w.x & 0xffff0000u)};
    a[1] += (f32x2){__uint_as_float(w.y << 16), __uint_as_float(w.y & 0xffff0000u)};
    a[2] += (f32x2){__uint_as_float(w.z << 16), __uint_as_float(w.z & 0xffff0000u)};
    a[3] += (f32x2){__uint_as_float(w.w << 16), __uint_as_float(w.w & 0xffff0000u)};
}

// ---------------------------------------------------------------------------
// FUSED layer GEMM (depth-2 prefetch K-loop, R18).
//   role 0 (z=0): x0[r] = A[r]@Wt0^T (+deg*bD0) + bC0, suppressed on labeled
//   role 1 (z=1): x0[idx[r]] = A[idx[r]]@Wt1^T (+deg*bD1) + bC1
// Writes disjoint by construction -> race-free in a single launch.
// Cout written COLUMN-BLOCKED x0b[col>>5][row][col&31] for the sliced seg.
// (R21: CSR fill plane removed — fill is now the atomic-free K2b kernel.)
// ---------------------------------------------------------------------------
template <bool DEG_BIAS>
__global__ __launch_bounds__(256) void mfma_gemm_fused(
    const __bf16* __restrict__ A,
    const __bf16* __restrict__ Wt0, const __bf16* __restrict__ Wt1,
    const float* __restrict__ bD0, const float* __restrict__ bD1,
    const float* __restrict__ bC0, const float* __restrict__ bC1,
    __bf16* __restrict__ Cout,
    const int* __restrict__ idx,     // pos (labeled rows)
    const int* __restrict__ degv,    // true degree per node
    const int* __restrict__ flags,   // 1 = labeled row
    int M)
{
    const int role = blockIdx.z;
    const int bx = blockIdx.x, by = blockIdx.y;
    if (role == 1 && bx >= N_LABEL / 64) return;

    const __bf16* Wt = role ? Wt1 : Wt0;
    const float*  bD = role ? bD1 : bD0;
    const float*  bC = role ? bC1 : bC0;

    __shared__ __bf16 As[3 * 64 * 32];    // 12 KB
    __shared__ __bf16 Bs[3 * 128 * 32];   // 24 KB
    __shared__ int s_idx[64];

    const int t    = threadIdx.x;
    const int lane = t & 63;
    const int wave = t >> 6;
    const int m0   = bx * 64;
    const int n0   = by * 128;

    if (role == 1) {
        if (t < 64) s_idx[t] = idx[m0 + t];
        __syncthreads();
    }

    const int arow  = t >> 2;
    const int acol8 = (t & 3) * 8;
    int anode;
    if (role == 1) {
        anode = s_idx[arow];
    } else {
        const int rg = m0 + arow;
        anode = (rg < M) ? rg : (M - 1);   // clamp; stores guarded below
    }
    const __bf16* aptr = A + (size_t)anode * HIDDEN + acol8;

    const __bf16* bptr[2];
    #pragma unroll
    for (int r = 0; r < 2; ++r) {
        const int c = r * 256 + t;
        bptr[r] = Wt + (size_t)(n0 + (c >> 2)) * HIDDEN + (c & 3) * 8;
    }

    f32x4 acc[8];
    #pragma unroll
    for (int i = 0; i < 8; ++i) acc[i] = (f32x4){0.f, 0.f, 0.f, 0.f};

    const int wm   = wave * 16;
    const int fm   = lane & 15;
    const int quad = lane >> 4;

    // ---- depth-2 prefetch pipeline (3 LDS buffers, counted vmcnt) ----
    const __bf16* bp0 = bptr[0];
    const __bf16* bp1 = bptr[1];
    #define STAGE_F(SB, K0)                                                    \
        { load_lds16(aptr + (K0), (void*)(As + (SB) * 2048 + (size_t)t * 8));  \
          load_lds16(bp0 + (K0),  (void*)(Bs + (SB) * 4096 + (size_t)t * 8));  \
          load_lds16(bp1 + (K0),  (void*)(Bs + (SB) * 4096 + (size_t)(256 + t) * 8)); }

    STAGE_F(0, 0)
    STAGE_F(1, 32)
    asm volatile("s_waitcnt vmcnt(3)" ::: "memory");
    __builtin_amdgcn_sched_barrier(0);
    __builtin_amdgcn_s_barrier();

    #pragma unroll
    for (int step = 0; step < NSTEP; ++step) {
        const int cur = step % 3;
        if (step + 2 < NSTEP) {
            const int nb = (step + 2) % 3;
            STAGE_F(nb, (step + 2) * 32)
        }
        const bf16x8 af = *(const bf16x8*)(As + cur * 2048 + (wm + fm) * 32 + quad * 8);
        bf16x8 bfr[8];
        #pragma unroll
        for (int nt = 0; nt < 8; ++nt)
            bfr[nt] = *(const bf16x8*)(Bs + cur * 4096 + (nt * 16 + fm) * 32 + quad * 8);
        #pragma unroll
        for (int nt = 0; nt < 8; ++nt)
            acc[nt] = __builtin_amdgcn_mfma_f32_16x16x32_bf16(
                af, bfr[nt], acc[nt], 0, 0, 0);
        if (step + 2 < NSTEP) asm volatile("s_waitcnt vmcnt(3)" ::: "memory");
        else                  asm volatile("s_waitcnt vmcnt(0)" ::: "memory");
        __builtin_amdgcn_sched_barrier(0);
        __builtin_amdgcn_s_barrier();
    }
    #undef STAGE_F

    // epilogue: C/D layout col=lane&15, row=quad*4+reg (m89/m91-verified)
    float bd[8], bc[8];
    #pragma unroll
    for (int nt = 0; nt < 8; ++nt) {
        const int col = n0 + nt * 16 + fm;
        bd[nt] = DEG_BIAS ? bD[col] : 0.f;
        bc[nt] = bC[col];
    }

    #pragma unroll
    for (int rg = 0; rg < 4; ++rg) {
        const int rloc = wm + quad * 4 + rg;
        int orow;
        if (role == 1) {
            orow = s_idx[rloc];
        } else {
            orow = m0 + rloc;
            if (orow >= M) continue;
            if (flags[orow]) continue;     // labeled: role-1 writes this row
        }
        float bscale = 0.f;
        if constexpr (DEG_BIAS)
            bscale = (float)degv[orow];
        #pragma unroll
        for (int nt = 0; nt < 8; ++nt) {
            const int cb = n0 + nt * 16;       // 16-col group, no 32-boundary cross
            float v = acc[nt][rg];
            if constexpr (DEG_BIAS) v += bscale * bd[nt];
            v += bc[nt];
            Cout[(size_t)(cb >> 5) * SLICE_ELEMS + (size_t)orow * 32
                 + (cb & 31) + fm] = (__bf16)v;
        }
    }
}

// ---------------------------------------------------------------------------
// Plain MFMA GEMM (product batch + final out GEMM), same depth-2 pipeline.
// ---------------------------------------------------------------------------
template <bool GATHER_A, bool DEG_BIAS, bool DEG_VIA_IDX, bool OUT_BF16, bool PROD_BATCH>
__global__ __launch_bounds__(256) void mfma_gemm(
    const __bf16* __restrict__ A_in,
    const __bf16* __restrict__ Wt_in,
    const float* __restrict__ biasD,
    void* __restrict__ Cout_in,
    const int* __restrict__ idx,
    const int* __restrict__ degv,
    int M)
{
    const __bf16* A  = A_in;
    const __bf16* Wt = Wt_in;
    void* Cout = Cout_in;
    if constexpr (PROD_BATCH) {
        const int z = blockIdx.z;
        A    = A_in  + (size_t)(3 * (1 + (z >> 1)) + (z & 1)) * WSZ;
        Wt   = Wt_in + (size_t)(z >> 1) * WSZ;
        Cout = (void*)((__bf16*)Cout_in + (size_t)z * WSZ);
    }

    __shared__ __bf16 As[3 * 64 * 32];
    __shared__ __bf16 Bs[3 * 128 * 32];
    __shared__ int s_idx[64];

    const int t    = threadIdx.x;
    const int lane = t & 63;
    const int wave = t >> 6;
    const int m0   = blockIdx.x * 64;
    const int n0   = blockIdx.y * 128;

    if constexpr (GATHER_A || DEG_VIA_IDX) {
        if (t < 64) s_idx[t] = idx[m0 + t];
        __syncthreads();
    }

    const int arow  = t >> 2;
    const int acol8 = (t & 3) * 8;
    int anode;
    if constexpr (GATHER_A) {
        anode = s_idx[arow];
    } else {
        const int rg = m0 + arow;
        anode = (rg < M) ? rg : (M - 1);
    }
    const __bf16* aptr = A + (size_t)anode * HIDDEN + acol8;

    const __bf16* bptr[2];
    #pragma unroll
    for (int r = 0; r < 2; ++r) {
        const int c = r * 256 + t;
        bptr[r] = Wt + (size_t)(n0 + (c >> 2)) * HIDDEN + (c & 3) * 8;
    }

    f32x4 acc[8];
    #pragma unroll
    for (int i = 0; i < 8; ++i) acc[i] = (f32x4){0.f, 0.f, 0.f, 0.f};

    const int wm   = wave * 16;
    const int fm   = lane & 15;
    const int quad = lane >> 4;

    const __bf16* bp0 = bptr[0];
    const __bf16* bp1 = bptr[1];
    #define STAGE_P(SB, K0)                                                    \
        { load_lds16(aptr + (K0), (void*)(As + (SB) * 2048 + (size_t)t * 8));  \
          load_lds16(bp0 + (K0),  (void*)(Bs + (SB) * 4096 + (size_t)t * 8));  \
          load_lds16(bp1 + (K0),  (void*)(Bs + (SB) * 4096 + (size_t)(256 + t) * 8)); }

    STAGE_P(0, 0)
    STAGE_P(1, 32)
    asm volatile("s_waitcnt vmcnt(3)" ::: "memory");
    __builtin_amdgcn_sched_barrier(0);
    __builtin_amdgcn_s_barrier();

    #pragma unroll
    for (int step = 0; step < NSTEP; ++step) {
        const int cur = step % 3;
        if (step + 2 < NSTEP) {
            const int nb = (step + 2) % 3;
            STAGE_P(nb, (step + 2) * 32)
        }
        const bf16x8 af = *(const bf16x8*)(As + cur * 2048 + (wm + fm) * 32 + quad * 8);
        bf16x8 bfr[8];
        #pragma unroll
        for (int nt = 0; nt < 8; ++nt)
            bfr[nt] = *(const bf16x8*)(Bs + cur * 4096 + (nt * 16 + fm) * 32 + quad * 8);
        #pragma unroll
        for (int nt = 0; nt < 8; ++nt)
            acc[nt] = __builtin_amdgcn_mfma_f32_16x16x32_bf16(
                af, bfr[nt], acc[nt], 0, 0, 0);
        if (step + 2 < NSTEP) asm volatile("s_waitcnt vmcnt(3)" ::: "memory");
        else                  asm volatile("s_waitcnt vmcnt(0)" ::: "memory");
        __builtin_amdgcn_sched_barrier(0);
        __builtin_amdgcn_s_barrier();
    }
    #undef STAGE_P

    float bd[8];
    #pragma unroll
    for (int nt = 0; nt < 8; ++nt)
        bd[nt] = DEG_BIAS ? biasD[n0 + nt * 16 + fm] : 0.f;

    #pragma unroll
    for (int rg = 0; rg < 4; ++rg) {
        const int rloc = wm + quad * 4 + rg;
        const int orow = m0 + rloc;
        if (!PROD_BATCH && orow >= M) continue;
        int dnode = orow;
        if constexpr (GATHER_A || DEG_VIA_IDX) dnode = s_idx[rloc];
        float bscale = 0.f;
        if constexpr (DEG_BIAS)
            bscale = (float)degv[dnode];
        #pragma unroll
        for (int nt = 0; nt < 8; ++nt) {
            const int col = n0 + nt * 16 + fm;
            float v = acc[nt][rg];
            if constexpr (DEG_BIAS) v += bscale * bd[nt];
            if constexpr (OUT_BF16)
                ((__bf16*)Cout)[(size_t)orow * HIDDEN + col] = (__bf16)v;
            else
                ((float*)Cout)[(size_t)orow * HIDDEN + col] = v;
        }
    }
}

// ---------------------------------------------------------------------------
// Weight prep + K1a bucket-histogram + x->bf16 convert, 114 z-slices.
// R21: NO GLOBAL ATOMICS anywhere in the CSR build (R6/R7 proved the 800K
// returning-atomic histogram is a ~40us structural floor on ANY atomic path
// and throttles co-resident streaming to 1.5 TB/s).
//  z 0..8  : T[z][n][k] = (bf16)W_z[k][n]  (transpose)
//  z 9..10 : cw_nt straight convert
//  z 11    : qprod
//  z 12..15: K1a — 196 blocks x 4096 edges: LDS histogram over 196 buckets
//            (bucket = dst>>8), plain store to blkbucket[blk][bucket].
//            Also: labeled flags + x0b sentinel-row zeroing.
//  z 16..113: xb16 = (bf16)x
// ---------------------------------------------------------------------------
__global__ __launch_bounds__(256) void wconv_kernel(
    const float* __restrict__ f0_w, const float* __restrict__ f1_w,
    const float* __restrict__ conv_w, const float* __restrict__ conv_b,
    __bf16* __restrict__ wt_all, __bf16* __restrict__ cw_nt,
    float* __restrict__ q,
    const int* __restrict__ edge_dst, const int* __restrict__ pos,
    int* __restrict__ blkbucket, int* __restrict__ flags,
    __bf16* __restrict__ x0b,
    const float* __restrict__ x32, __bf16* __restrict__ xb16)
{
    const int z = blockIdx.z;
    const int tx = threadIdx.x, ty = threadIdx.y;
    const int tt = ty * 32 + tx;

    if (z >= 16) {
        // x -> bf16 conversion (98 planes x 64 blocks x 256 thr x 8 elems)
        const int c = (z - 16) * 64 + blockIdx.x * 8 + blockIdx.y;
        const size_t base = ((size_t)c * 256 + tt) * 8;
        if (base < (size_t)N_NODES * HIDDEN) {
            const float4 u0 = *(const float4*)(x32 + base);
            const float4 u1 = *(const float4*)(x32 + base + 4);
            bf16x8 w = {(__bf16)u0.x, (__bf16)u0.y, (__bf16)u0.z, (__bf16)u0.w,
                        (__bf16)u1.x, (__bf16)u1.y, (__bf16)u1.z, (__bf16)u1.w};
            *(bf16x8*)(xb16 + base) = w;
        }
        return;
    }
    if (z >= 12) {
        // ---- K1a: per-block LDS bucket histogram ----
        __shared__ int lhist[256];
        const int blk = (z - 12) * 64 + blockIdx.x * 8 + blockIdx.y;
        if (blk >= EDGE_BLOCKS) return;
        if (blk == 0 && tt < 256) {
            // zero the sentinel row (node N_NODES) in each of the 8 slices
            const int sl = tt >> 5, c = tt & 31;
            x0b[(size_t)sl * SLICE_ELEMS + (size_t)N_NODES * 32 + c] = (__bf16)0.f;
        }
        lhist[tt] = 0;
        __syncthreads();
        const int e0 = blk * 4096;
        #pragma unroll
        for (int j = 0; j < 16; ++j) {
            const int e = e0 + j * 256 + tt;
            if (e < N_EDGES) atomicAdd(&lhist[edge_dst[e] >> 8], 1);
            if (e < N_LABEL) flags[pos[e]] = 1;   // benign dup writes
        }
        __syncthreads();
        if (tt < NBUCKET) blkbucket[blk * 256 + tt] = lhist[tt];
        return;
    }

    const int kx = blockIdx.x * 32, nx = blockIdx.y * 32;

    if (z < 9) {
        const int layer = z / 3, which = z % 3;
        const float* W = ((which == 0) ? f0_w : (which == 1) ? f1_w : conv_w)
                         + (size_t)layer * WSZ;
        __bf16* T = wt_all + (size_t)z * WSZ;

        __shared__ float tile[32][33];
        for (int i = ty; i < 32; i += 8)
            tile[i][tx] = W[(size_t)(kx + i) * HIDDEN + nx + tx];
        __syncthreads();
        for (int i = ty; i < 32; i += 8)
            T[(size_t)(nx + i) * HIDDEN + kx + tx] = (__bf16)tile[tx][i];
    } else if (z < 11) {
        const int layer = z - 9;
        const float* W = conv_w + (size_t)layer * WSZ;
        __bf16* T = cw_nt + (size_t)layer * WSZ;
        for (int i = ty; i < 32; i += 8)
            T[(size_t)(kx + i) * HIDDEN + nx + tx] =
                (__bf16)W[(size_t)(kx + i) * HIDDEN + nx + tx];
    } else {
        if (blockIdx.x >= 4 || blockIdx.y != 0) return;
        const int zq = blockIdx.x;
        const int l = zq >> 1, branch = zq & 1;
        const float* cb = conv_b + (size_t)l * HIDDEN;
        const float* W  = (branch ? f1_w : f0_w) + (size_t)(l + 1) * WSZ;
        const int n = tt;
        float s = 0.f;
        #pragma unroll 4
        for (int k = 0; k < HIDDEN; ++k)
            s += cb[k] * W[(size_t)k * HIDDEN + n];
        q[(size_t)zq * HIDDEN + n] = s;
    }
}

__device__ __forceinline__ int block_incl_scan(int v, int* s, int t)
{
    s[t] = v; __syncthreads();
    #pragma unroll
    for (int off = 1; off < 256; off <<= 1) {
        int add = (t >= off) ? s[t - off] : 0;
        __syncthreads();
        s[t] += add;
        __syncthreads();
    }
    return s[t];
}

// K1b: 2D scan of blkbucket -> per-(block,bucket) base + bucket base/size.
// Single block; thread b owns bucket b. Zero global atomics.
__global__ __launch_bounds__(256) void k1b_kernel(
    const int* __restrict__ blkbucket, int* __restrict__ blkbase,
    int* __restrict__ bucket_base, int* __restrict__ bucket_size)
{
    __shared__ int s[256];
    const int t = threadIdx.x;
    int sum = 0;
    if (t < NBUCKET) {
        for (int blk = 0; blk < EDGE_BLOCKS; ++blk) {
            blkbase[blk * 256 + t] = sum;
            sum += blkbucket[blk * 256 + t];
        }
    }
    const int incl = block_incl_scan(sum, s, t);
    const int bb = incl - sum;
    if (t < NBUCKET) {
        bucket_base[t] = bb;
        bucket_size[t] = sum;
        for (int blk = 0; blk < EDGE_BLOCKS; ++blk)
            blkbase[blk * 256 + t] += bb;
    }
}

// K1c: scatter edges into bucket_buf (packed src | (dst&255)<<16).
// LDS cursor per bucket; blocks write disjoint regions by construction.
__global__ __launch_bounds__(256) void k1c_kernel(
    const int* __restrict__ esrc, const int* __restrict__ edst,
    const int* __restrict__ blkbase, unsigned int* __restrict__ bucket_buf)
{
    __shared__ int cur[256];
    const int blk = blockIdx.x;
    const int t = threadIdx.x;
    cur[t] = (t < NBUCKET) ? blkbase[blk * 256 + t] : 0;
    __syncthreads();
    const int e0 = blk * 4096;
    #pragma unroll
    for (int j = 0; j < 16; ++j) {
        const int e = e0 + j * 256 + t;
        if (e < N_EDGES) {
            const int d = edst[e];
            const int p = atomicAdd(&cur[d >> 8], 1);
            bucket_buf[p] = (unsigned int)esrc[e] | ((unsigned int)(d & 255) << 16);
        }
    }
}

// K2a: per-bucket LDS node-count -> counts[] (true degree) + padded local
// exclusive scan (replaces scan1). Bucket b == scan block b (256 nodes).
__global__ __launch_bounds__(256) void k2a_kernel(
    const unsigned int* __restrict__ bucket_buf,
    const int* __restrict__ bucket_base, const int* __restrict__ bucket_size,
    int* __restrict__ counts, int* __restrict__ offs_local,
    int* __restrict__ bsum)
{
    __shared__ int lcnt[256];
    __shared__ int s[256];
    const int b = blockIdx.x;
    const int t = threadIdx.x;
    lcnt[t] = 0;
    __syncthreads();
    const int bb = bucket_base[b], sz = bucket_size[b];
    for (int j = t; j < sz; j += 256)
        atomicAdd(&lcnt[bucket_buf[bb + j] >> 16], 1);
    __syncthreads();
    const int cnt = lcnt[t];
    counts[b * 256 + t] = cnt;
    const int pv = (cnt + 7) & ~7;
    const int incl = block_incl_scan(pv, s, t);
    offs_local[b * 256 + t] = incl - pv;
    if (t == 255) bsum[b] = incl;
}

__global__ __launch_bounds__(256) void scan2_kernel(
    const int* __restrict__ bsum, int* __restrict__ bbase)
{
    __shared__ int s[256];
    const int t = threadIdx.x;
    const int v = (t < SCAN_BLOCKS) ? bsum[t] : 0;
    int incl = block_incl_scan(v, s, t);
    bbase[t] = incl - v;
}

// K2b: finalize offs, fill src_sorted via LDS cursors, sentinel pads.
// Output region per bucket is contiguous -> writes combine to full lines
// (the old atomic fill's 16x partial-line writeback disappears).
__global__ __launch_bounds__(256) void k2b_kernel(
    const unsigned int* __restrict__ bucket_buf,
    const int* __restrict__ bucket_base, const int* __restrict__ bucket_size,
    const int* __restrict__ offs_local, const int* __restrict__ bbase,
    int* __restrict__ offs, int* __restrict__ src_sorted)
{
    __shared__ int cur[256];
    const int b = blockIdx.x;
    const int t = threadIdx.x;
    const int off = offs_local[b * 256 + t] + bbase[b];
    offs[b * 256 + t] = off;
    cur[t] = off;
    __syncthreads();
    const int bb = bucket_base[b], sz = bucket_size[b];
    for (int j = t; j < sz; j += 256) {
        const unsigned int u = bucket_buf[bb + j];
        const int p = atomicAdd(&cur[u >> 16], 1);
        src_sorted[p] = (int)(u & 0xffffu);
    }
    __syncthreads();
    const int end = cur[t];
    const int pe  = off + ((end - off + 7) & ~7);
    for (int j = end; j < pe; ++j) src_sorted[j] = N_NODES;
}

// ---------------------------------------------------------------------------
// XCD-sliced pull-mode segment sum, branch-free window-8 (R15).
// slice = blockIdx.x & 7 pins each 3.2MB column slice to one XCD L2.
// ---------------------------------------------------------------------------
template <bool COMPACT>
__global__ __launch_bounds__(256) void seg_slice_kernel(
    const __bf16* __restrict__ x0b,
    const int* __restrict__ srcs,
    const int* __restrict__ offs,      // PADDED offsets (multiples of 8)
    const int* __restrict__ nodelist,
    __bf16* __restrict__ out)
{
    const int slice = blockIdx.x & 7;
    const int chunk = blockIdx.x >> 3;
    const int t    = threadIdx.x;
    const int wave = t >> 6;
    const int lane = t & 63;
    const int g    = lane >> 2;      // 16 groups per wave
    const int li   = lane & 3;       // 4 lanes per dst row, 8 cols each
    const int rw   = chunk * 64 + wave * 16 + g;
    if (!COMPACT && rw >= N_NODES) return;

    const int d    = COMPACT ? nodelist[rw] : rw;
    const int beg  = offs[d];
    const int pdeg = offs[d + 1] - beg;   // multiple of 8

    const char* xb = (const char*)(x0b + (size_t)slice * SLICE_ELEMS);
    const uint32_t lioff = (uint32_t)li * 16u;
    const int* sp = srcs + beg;           // 32B-aligned

    f32x2 a[4];
    #pragma unroll
    for (int j = 0; j < 4; ++j) a[j] = (f32x2){0.f, 0.f};

    int4 j0, j1;
    if (pdeg > 0) {
        j0 = *(const int4*)(sp);
        j1 = *(const int4*)(sp + 4);
    }

    for (int base = 0; base < pdeg; base += 8) {
        const int4 k0 = j0, k1 = j1;
        if (base + 8 < pdeg) {            // prefetch next window's indices
            j0 = *(const int4*)(sp + base + 8);
            j1 = *(const int4*)(sp + base + 12);
        }
        const uint4 c0 = *(const uint4*)(xb + (((uint32_t)k0.x << 6) + lioff));
        const uint4 c1 = *(const uint4*)(xb + (((uint32_t)k0.y << 6) + lioff));
        const uint4 c2 = *(const uint4*)(xb + (((uint32_t)k0.z << 6) + lioff));
        const uint4 c3 = *(const uint4*)(xb + (((uint32_t)k0.w << 6) + lioff));
        const uint4 c4 = *(const uint4*)(xb + (((uint32_t)k1.x << 6) + lioff));
        const uint4 c5 = *(const uint4*)(xb + (((uint32_t)k1.y << 6) + lioff));
        const uint4 c6 = *(const uint4*)(xb + (((uint32_t)k1.z << 6) + lioff));
        const uint4 c7 = *(const uint4*)(xb + (((uint32_t)k1.w << 6) + lioff));
        acc8(c0, a); acc8(c1, a); acc8(c2, a); acc8(c3, a);
        acc8(c4, a); acc8(c5, a); acc8(c6, a); acc8(c7, a);
    }

    bf16x8 o;
    #pragma unroll
    for (int j = 0; j < 4; ++j) {
        o[2 * j]     = (__bf16)a[j].x;
        o[2 * j + 1] = (__bf16)a[j].y;
    }
    *(bf16x8*)(out + (size_t)rw * HIDDEN + (slice << 5) + li * 8) = o;
}

extern "C" void kernel_launch(void* const* d_in, const int* in_sizes, int n_in,
                              void* d_out, int out_size, void* d_ws, size_t ws_size,
                              hipStream_t stream)
{
    const float* x       = (const float*)d_in[0];
    const float* f0_w    = (const float*)d_in[1];
    const float* f0_b    = (const float*)d_in[2];
    const float* f1_w    = (const float*)d_in[3];
    const float* f1_b    = (const float*)d_in[4];
    const float* conv_w  = (const float*)d_in[5];
    const float* conv_b  = (const float*)d_in[6];
    const int*   edge_src = (const int*)d_in[7];
    const int*   edge_dst = (const int*)d_in[8];
    const int*   pos      = (const int*)d_in[9];
    float* out = (float*)d_out;

    const size_t buf = (size_t)N_NODES * HIDDEN;   // 12.8M elems

    char* p = (char*)d_ws;
    __bf16* bufA   = (__bf16*)p; p += buf * 2;                 // 25.6 MB (xb16 / S)
    __bf16* bufB   = (__bf16*)p; p += SLICE_ELEMS * 8 * 2;     // 25.6 MB+ (blocked x0)
    __bf16* s_lbl  = (__bf16*)p; p += (size_t)N_LABEL * HIDDEN * 2;  // 4 MB
    __bf16* wt_all = (__bf16*)p; p += (size_t)9 * WSZ * 2;
    __bf16* prod   = (__bf16*)p; p += (size_t)4 * WSZ * 2;
    __bf16* cw_nt  = (__bf16*)p; p += (size_t)2 * WSZ * 2;
    float*  qv     = (float*)p;  p += (size_t)4 * HIDDEN * 4;
    int* flags      = (int*)p;  p += NPAD * 4;                 // labeled-row bitmap
    int* counts     = (int*)p;  p += NPAD * 4;                 // true degree
    int* offs_local = (int*)p;  p += NPAD * 4;
    int* offs       = (int*)p;  p += NPAD * 4;                 // PADDED offsets
    int* bsum       = (int*)p;  p += 256 * 4;
    int* bbase      = (int*)p;  p += 256 * 4;
    int* blkbucket  = (int*)p;  p += (size_t)EDGE_BLOCKS * 256 * 4;  // 200 KB
    int* blkbase    = (int*)p;  p += (size_t)EDGE_BLOCKS * 256 * 4;  // 200 KB
    int* bucket_base= (int*)p;  p += 256 * 4;
    int* bucket_size= (int*)p;  p += 256 * 4;
    unsigned int* bucket_buf = (unsigned int*)p; p += (size_t)N_EDGES * 4;  // 3.2 MB
    int* src_sorted = (int*)p;  p += (size_t)(N_EDGES + 7 * NPAD) * 4;

    // ---- CSR build: deterministic two-level counting sort, 0 global atomics
    hipMemsetAsync(flags, 0, NPAD * sizeof(int), stream);
    wconv_kernel<<<dim3(8, 8, 114), dim3(32, 8), 0, stream>>>(
        f0_w, f1_w, conv_w, conv_b, wt_all, cw_nt, qv,
        edge_dst, pos, blkbucket, flags, bufB, x, bufA);
    k1b_kernel<<<1, 256, 0, stream>>>(blkbucket, blkbase, bucket_base, bucket_size);
    k1c_kernel<<<EDGE_BLOCKS, 256, 0, stream>>>(edge_src, edge_dst, blkbase, bucket_buf);
    k2a_kernel<<<NBUCKET, 256, 0, stream>>>(
        bucket_buf, bucket_base, bucket_size, counts, offs_local, bsum);
    scan2_kernel<<<1, 256, 0, stream>>>(bsum, bbase);
    k2b_kernel<<<NBUCKET, 256, 0, stream>>>(
        bucket_buf, bucket_base, bucket_size, offs_local, bbase, offs, src_sorted);

    // all 4 products prod_t[z] = (Cw_l · F_{l+1})^T in ONE batched launch
    mfma_gemm<false, false, false, true, true><<<dim3(4, 2, 4), 256, 0, stream>>>(
        wt_all, cw_nt, nullptr, prod, nullptr, nullptr, HIDDEN);

    const dim3 fused_grid(782, 2, 2);   // z=0 full, z=1 label
    const dim3 lbl_grid(128, 2);

    __bf16* cur = bufA;              // S buffer (= xb16 at layer 0)
    __bf16* tmp = bufB;              // x0 buffer, COLUMN-BLOCKED layout

    for (int l = 0; l < N_LAYERS; ++l) {
        const float* B0 = f0_b + (size_t)l * HIDDEN;
        const float* B1 = f1_b + (size_t)l * HIDDEN;

        if (l == 0) {
            // x0 = xb16@F0_0+b0 (all, minus labeled) ∪ xb16@F1_0+b1 (labeled)
            mfma_gemm_fused<false><<<fused_grid, 256, 0, stream>>>(
                bufA, wt_all + 0 * WSZ, wt_all + 1 * WSZ,
                nullptr, nullptr, B0, B1, tmp, pos, counts, flags, N_NODES);
        } else {
            // x0 = S@(Cw·F0_l)+deg*q0+b0 ∪ S@(Cw·F1_l)+deg*q1+b1 (folded conv)
            const int z0 = (l - 1) * 2;
            mfma_gemm_fused<true><<<fused_grid, 256, 0, stream>>>(
                cur, prod + (size_t)z0 * WSZ, prod + (size_t)(z0 + 1) * WSZ,
                qv + (size_t)z0 * HIDDEN, qv + (size_t)(z0 + 1) * HIDDEN,
                B0, B1, tmp, pos, counts, flags, N_NODES);
        }

        if (l < N_LAYERS - 1) {
            // S = segment_sum(x0[src]) at ALL nodes (tmp -> cur), XCD-sliced
            seg_slice_kernel<false><<<8 * SEG_CHUNKS, 256, 0, stream>>>(
                tmp, src_sorted, offs, nullptr, cur);
        } else {
            // S only at labeled dst nodes (tmp -> s_lbl, compact pos order)
            seg_slice_kernel<true><<<8 * (N_LABEL / 64), 256, 0, stream>>>(
                tmp, src_sorted, offs, pos, s_lbl);
            // out[i] = S_lbl[i] @ Cw_2 + deg[pos[i]]*cb_2  -> d_out (fp32)
            mfma_gemm<false, true, true, false, false><<<lbl_grid, 256, 0, stream>>>(
                s_lbl, wt_all + (size_t)(2 * 3 + 2) * WSZ,
                conv_b + (size_t)2 * HIDDEN, out, pos, counts, N_LABEL);
        }
    }
}

// Round 9
// 329.094 us; speedup vs baseline: 1.1255x; 1.1255x over previous
//
#include <hip/hip_runtime.h>
#include <hip/hip_bf16.h>

#define N_NODES 50000
#define N_EDGES 800000
#define HIDDEN  256
#define N_LAYERS 3
#define N_PAIRS 4096
#define N_LABEL 8192            // 2*N_PAIRS labeled rows
#define NPAD    50176           // 196*256, padded node count for the scan
#define SCAN_BLOCKS (NPAD / 256) // 196
#define WSZ (HIDDEN * HIDDEN)    // 65536 elems per weight matrix
#define NSTEP (HIDDEN / 32)      // 8 K-steps
#define NBUCKET 196              // dst>>8 buckets (256 nodes each)
#define EDGE_BLOCKS 196          // K1 blocks x 4096 edges = 802816 >= N_EDGES

// Column-blocked x0 layout for the XCD-sliced segment sum:
//   x0b[slice][node][32], slice = col>>5. One slice = 3.2 MB < 4 MB XCD L2.
// Row N_NODES is an all-zero SENTINEL row: CSR segments are padded to a
// multiple of 8 with edges pointing at it -> branch-free window-8 seg loop.
// R22: src_sorted is u16 (ids <= 50000 < 65536) -> one 16B load per window.
#define NROWPAD (N_NODES + 1)
#define SLICE_ELEMS ((size_t)NROWPAD * 32)
#define SEG_CHUNKS ((N_NODES + 63) / 64)   // 782

typedef __bf16 bf16x8 __attribute__((ext_vector_type(8)));
typedef float  f32x4  __attribute__((ext_vector_type(4)));
typedef float  f32x2  __attribute__((ext_vector_type(2)));

__device__ __forceinline__ void load_lds16(const void* g, void* l) {
    __builtin_amdgcn_global_load_lds(
        (const __attribute__((address_space(1))) void*)g,
        (__attribute__((address_space(3))) void*)l, 16, 0, 0);
}

// accumulate 8 bf16 (as uint4) into 4 packed f32 pairs (v_pk_add_f32 path)
__device__ __forceinline__ void acc8(const uint4 w, f32x2* a) {
    a[0] += (f32x2){__uint_as_float(w.x << 16), __uint_as_float(w.x & 0xffff0000u)};
    a[1] += (f32x2){__uint_as_float(w.y << 16), __uint_as_float(w.y & 0xffff0000u)};
    a[2] += (f32x2){__uint_as_float(w.z << 16), __uint_as_float(w.z & 0xffff0000u)};
    a[3] += (f32x2){__uint_as_float(w.w << 16), __uint_as_float(w.w & 0xffff0000u)};
}

// ---------------------------------------------------------------------------
// FUSED layer GEMM (depth-2 prefetch K-loop, R18).
//   role 0 (z=0): x0[r] = A[r]@Wt0^T (+deg*bD0) + bC0, suppressed on labeled
//   role 1 (z=1): x0[idx[r]] = A[idx[r]]@Wt1^T (+deg*bD1) + bC1
// Writes disjoint by construction -> race-free in a single launch.
// Cout written COLUMN-BLOCKED x0b[col>>5][row][col&31] for the sliced seg.
// ---------------------------------------------------------------------------
template <bool DEG_BIAS>
__global__ __launch_bounds__(256) void mfma_gemm_fused(
    const __bf16* __restrict__ A,
    const __bf16* __restrict__ Wt0, const __bf16* __restrict__ Wt1,
    const float* __restrict__ bD0, const float* __restrict__ bD1,
    const float* __restrict__ bC0, const float* __restrict__ bC1,
    __bf16* __restrict__ Cout,
    const int* __restrict__ idx,     // pos (labeled rows)
    const int* __restrict__ degv,    // true degree per node
    const int* __restrict__ flags,   // 1 = labeled row
    int M)
{
    const int role = blockIdx.z;
    const int bx = blockIdx.x, by = blockIdx.y;
    if (role == 1 && bx >= N_LABEL / 64) return;

    const __bf16* Wt = role ? Wt1 : Wt0;
    const float*  bD = role ? bD1 : bD0;
    const float*  bC = role ? bC1 : bC0;

    __shared__ __bf16 As[3 * 64 * 32];    // 12 KB
    __shared__ __bf16 Bs[3 * 128 * 32];   // 24 KB
    __shared__ int s_idx[64];

    const int t    = threadIdx.x;
    const int lane = t & 63;
    const int wave = t >> 6;
    const int m0   = bx * 64;
    const int n0   = by * 128;

    if (role == 1) {
        if (t < 64) s_idx[t] = idx[m0 + t];
        __syncthreads();
    }

    const int arow  = t >> 2;
    const int acol8 = (t & 3) * 8;
    int anode;
    if (role == 1) {
        anode = s_idx[arow];
    } else {
        const int rg = m0 + arow;
        anode = (rg < M) ? rg : (M - 1);   // clamp; stores guarded below
    }
    const __bf16* aptr = A + (size_t)anode * HIDDEN + acol8;

    const __bf16* bptr[2];
    #pragma unroll
    for (int r = 0; r < 2; ++r) {
        const int c = r * 256 + t;
        bptr[r] = Wt + (size_t)(n0 + (c >> 2)) * HIDDEN + (c & 3) * 8;
    }

    f32x4 acc[8];
    #pragma unroll
    for (int i = 0; i < 8; ++i) acc[i] = (f32x4){0.f, 0.f, 0.f, 0.f};

    const int wm   = wave * 16;
    const int fm   = lane & 15;
    const int quad = lane >> 4;

    // ---- depth-2 prefetch pipeline (3 LDS buffers, counted vmcnt) ----
    const __bf16* bp0 = bptr[0];
    const __bf16* bp1 = bptr[1];
    #define STAGE_F(SB, K0)                                                    \
        { load_lds16(aptr + (K0), (void*)(As + (SB) * 2048 + (size_t)t * 8));  \
          load_lds16(bp0 + (K0),  (void*)(Bs + (SB) * 4096 + (size_t)t * 8));  \
          load_lds16(bp1 + (K0),  (void*)(Bs + (SB) * 4096 + (size_t)(256 + t) * 8)); }

    STAGE_F(0, 0)
    STAGE_F(1, 32)
    asm volatile("s_waitcnt vmcnt(3)" ::: "memory");
    __builtin_amdgcn_sched_barrier(0);
    __builtin_amdgcn_s_barrier();

    #pragma unroll
    for (int step = 0; step < NSTEP; ++step) {
        const int cur = step % 3;
        if (step + 2 < NSTEP) {
            const int nb = (step + 2) % 3;
            STAGE_F(nb, (step + 2) * 32)
        }
        const bf16x8 af = *(const bf16x8*)(As + cur * 2048 + (wm + fm) * 32 + quad * 8);
        bf16x8 bfr[8];
        #pragma unroll
        for (int nt = 0; nt < 8; ++nt)
            bfr[nt] = *(const bf16x8*)(Bs + cur * 4096 + (nt * 16 + fm) * 32 + quad * 8);
        #pragma unroll
        for (int nt = 0; nt < 8; ++nt)
            acc[nt] = __builtin_amdgcn_mfma_f32_16x16x32_bf16(
                af, bfr[nt], acc[nt], 0, 0, 0);
        if (step + 2 < NSTEP) asm volatile("s_waitcnt vmcnt(3)" ::: "memory");
        else                  asm volatile("s_waitcnt vmcnt(0)" ::: "memory");
        __builtin_amdgcn_sched_barrier(0);
        __builtin_amdgcn_s_barrier();
    }
    #undef STAGE_F

    // epilogue: C/D layout col=lane&15, row=quad*4+reg (m89/m91-verified)
    float bd[8], bc[8];
    #pragma unroll
    for (int nt = 0; nt < 8; ++nt) {
        const int col = n0 + nt * 16 + fm;
        bd[nt] = DEG_BIAS ? bD[col] : 0.f;
        bc[nt] = bC[col];
    }

    #pragma unroll
    for (int rg = 0; rg < 4; ++rg) {
        const int rloc = wm + quad * 4 + rg;
        int orow;
        if (role == 1) {
            orow = s_idx[rloc];
        } else {
            orow = m0 + rloc;
            if (orow >= M) continue;
            if (flags[orow]) continue;     // labeled: role-1 writes this row
        }
        float bscale = 0.f;
        if constexpr (DEG_BIAS)
            bscale = (float)degv[orow];
        #pragma unroll
        for (int nt = 0; nt < 8; ++nt) {
            const int cb = n0 + nt * 16;       // 16-col group, no 32-boundary cross
            float v = acc[nt][rg];
            if constexpr (DEG_BIAS) v += bscale * bd[nt];
            v += bc[nt];
            Cout[(size_t)(cb >> 5) * SLICE_ELEMS + (size_t)orow * 32
                 + (cb & 31) + fm] = (__bf16)v;
        }
    }
}

// ---------------------------------------------------------------------------
// Plain MFMA GEMM (product batch + final out GEMM), same depth-2 pipeline.
// ---------------------------------------------------------------------------
template <bool GATHER_A, bool DEG_BIAS, bool DEG_VIA_IDX, bool OUT_BF16, bool PROD_BATCH>
__global__ __launch_bounds__(256) void mfma_gemm(
    const __bf16* __restrict__ A_in,
    const __bf16* __restrict__ Wt_in,
    const float* __restrict__ biasD,
    void* __restrict__ Cout_in,
    const int* __restrict__ idx,
    const int* __restrict__ degv,
    int M)
{
    const __bf16* A  = A_in;
    const __bf16* Wt = Wt_in;
    void* Cout = Cout_in;
    if constexpr (PROD_BATCH) {
        const int z = blockIdx.z;
        A    = A_in  + (size_t)(3 * (1 + (z >> 1)) + (z & 1)) * WSZ;
        Wt   = Wt_in + (size_t)(z >> 1) * WSZ;
        Cout = (void*)((__bf16*)Cout_in + (size_t)z * WSZ);
    }

    __shared__ __bf16 As[3 * 64 * 32];
    __shared__ __bf16 Bs[3 * 128 * 32];
    __shared__ int s_idx[64];

    const int t    = threadIdx.x;
    const int lane = t & 63;
    const int wave = t >> 6;
    const int m0   = blockIdx.x * 64;
    const int n0   = blockIdx.y * 128;

    if constexpr (GATHER_A || DEG_VIA_IDX) {
        if (t < 64) s_idx[t] = idx[m0 + t];
        __syncthreads();
    }

    const int arow  = t >> 2;
    const int acol8 = (t & 3) * 8;
    int anode;
    if constexpr (GATHER_A) {
        anode = s_idx[arow];
    } else {
        const int rg = m0 + arow;
        anode = (rg < M) ? rg : (M - 1);
    }
    const __bf16* aptr = A + (size_t)anode * HIDDEN + acol8;

    const __bf16* bptr[2];
    #pragma unroll
    for (int r = 0; r < 2; ++r) {
        const int c = r * 256 + t;
        bptr[r] = Wt + (size_t)(n0 + (c >> 2)) * HIDDEN + (c & 3) * 8;
    }

    f32x4 acc[8];
    #pragma unroll
    for (int i = 0; i < 8; ++i) acc[i] = (f32x4){0.f, 0.f, 0.f, 0.f};

    const int wm   = wave * 16;
    const int fm   = lane & 15;
    const int quad = lane >> 4;

    const __bf16* bp0 = bptr[0];
    const __bf16* bp1 = bptr[1];
    #define STAGE_P(SB, K0)                                                    \
        { load_lds16(aptr + (K0), (void*)(As + (SB) * 2048 + (size_t)t * 8));  \
          load_lds16(bp0 + (K0),  (void*)(Bs + (SB) * 4096 + (size_t)t * 8));  \
          load_lds16(bp1 + (K0),  (void*)(Bs + (SB) * 4096 + (size_t)(256 + t) * 8)); }

    STAGE_P(0, 0)
    STAGE_P(1, 32)
    asm volatile("s_waitcnt vmcnt(3)" ::: "memory");
    __builtin_amdgcn_sched_barrier(0);
    __builtin_amdgcn_s_barrier();

    #pragma unroll
    for (int step = 0; step < NSTEP; ++step) {
        const int cur = step % 3;
        if (step + 2 < NSTEP) {
            const int nb = (step + 2) % 3;
            STAGE_P(nb, (step + 2) * 32)
        }
        const bf16x8 af = *(const bf16x8*)(As + cur * 2048 + (wm + fm) * 32 + quad * 8);
        bf16x8 bfr[8];
        #pragma unroll
        for (int nt = 0; nt < 8; ++nt)
            bfr[nt] = *(const bf16x8*)(Bs + cur * 4096 + (nt * 16 + fm) * 32 + quad * 8);
        #pragma unroll
        for (int nt = 0; nt < 8; ++nt)
            acc[nt] = __builtin_amdgcn_mfma_f32_16x16x32_bf16(
                af, bfr[nt], acc[nt], 0, 0, 0);
        if (step + 2 < NSTEP) asm volatile("s_waitcnt vmcnt(3)" ::: "memory");
        else                  asm volatile("s_waitcnt vmcnt(0)" ::: "memory");
        __builtin_amdgcn_sched_barrier(0);
        __builtin_amdgcn_s_barrier();
    }
    #undef STAGE_P

    float bd[8];
    #pragma unroll
    for (int nt = 0; nt < 8; ++nt)
        bd[nt] = DEG_BIAS ? biasD[n0 + nt * 16 + fm] : 0.f;

    #pragma unroll
    for (int rg = 0; rg < 4; ++rg) {
        const int rloc = wm + quad * 4 + rg;
        const int orow = m0 + rloc;
        if (!PROD_BATCH && orow >= M) continue;
        int dnode = orow;
        if constexpr (GATHER_A || DEG_VIA_IDX) dnode = s_idx[rloc];
        float bscale = 0.f;
        if constexpr (DEG_BIAS)
            bscale = (float)degv[dnode];
        #pragma unroll
        for (int nt = 0; nt < 8; ++nt) {
            const int col = n0 + nt * 16 + fm;
            float v = acc[nt][rg];
            if constexpr (DEG_BIAS) v += bscale * bd[nt];
            if constexpr (OUT_BF16)
                ((__bf16*)Cout)[(size_t)orow * HIDDEN + col] = (__bf16)v;
            else
                ((float*)Cout)[(size_t)orow * HIDDEN + col] = v;
        }
    }
}

// ---------------------------------------------------------------------------
// Weight prep + K1a bucket-histogram + x->bf16 convert, 114 z-slices.
// Zero global atomics in the whole CSR build (R21).
// ---------------------------------------------------------------------------
__global__ __launch_bounds__(256) void wconv_kernel(
    const float* __restrict__ f0_w, const float* __restrict__ f1_w,
    const float* __restrict__ conv_w, const float* __restrict__ conv_b,
    __bf16* __restrict__ wt_all, __bf16* __restrict__ cw_nt,
    float* __restrict__ q,
    const int* __restrict__ edge_dst, const int* __restrict__ pos,
    int* __restrict__ blkbucket, int* __restrict__ flags,
    __bf16* __restrict__ x0b,
    const float* __restrict__ x32, __bf16* __restrict__ xb16)
{
    const int z = blockIdx.z;
    const int tx = threadIdx.x, ty = threadIdx.y;
    const int tt = ty * 32 + tx;

    if (z >= 16) {
        // x -> bf16 conversion (98 planes x 64 blocks x 256 thr x 8 elems)
        const int c = (z - 16) * 64 + blockIdx.x * 8 + blockIdx.y;
        const size_t base = ((size_t)c * 256 + tt) * 8;
        if (base < (size_t)N_NODES * HIDDEN) {
            const float4 u0 = *(const float4*)(x32 + base);
            const float4 u1 = *(const float4*)(x32 + base + 4);
            bf16x8 w = {(__bf16)u0.x, (__bf16)u0.y, (__bf16)u0.z, (__bf16)u0.w,
                        (__bf16)u1.x, (__bf16)u1.y, (__bf16)u1.z, (__bf16)u1.w};
            *(bf16x8*)(xb16 + base) = w;
        }
        return;
    }
    if (z >= 12) {
        // ---- K1a: per-block LDS bucket histogram ----
        __shared__ int lhist[256];
        const int blk = (z - 12) * 64 + blockIdx.x * 8 + blockIdx.y;
        if (blk >= EDGE_BLOCKS) return;
        if (blk == 0 && tt < 256) {
            // zero the sentinel row (node N_NODES) in each of the 8 slices
            const int sl = tt >> 5, c = tt & 31;
            x0b[(size_t)sl * SLICE_ELEMS + (size_t)N_NODES * 32 + c] = (__bf16)0.f;
        }
        lhist[tt] = 0;
        __syncthreads();
        const int e0 = blk * 4096;
        #pragma unroll
        for (int j = 0; j < 16; ++j) {
            const int e = e0 + j * 256 + tt;
            if (e < N_EDGES) atomicAdd(&lhist[edge_dst[e] >> 8], 1);
            if (e < N_LABEL) flags[pos[e]] = 1;   // benign dup writes
        }
        __syncthreads();
        if (tt < NBUCKET) blkbucket[blk * 256 + tt] = lhist[tt];
        return;
    }

    const int kx = blockIdx.x * 32, nx = blockIdx.y * 32;

    if (z < 9) {
        const int layer = z / 3, which = z % 3;
        const float* W = ((which == 0) ? f0_w : (which == 1) ? f1_w : conv_w)
                         + (size_t)layer * WSZ;
        __bf16* T = wt_all + (size_t)z * WSZ;

        __shared__ float tile[32][33];
        for (int i = ty; i < 32; i += 8)
            tile[i][tx] = W[(size_t)(kx + i) * HIDDEN + nx + tx];
        __syncthreads();
        for (int i = ty; i < 32; i += 8)
            T[(size_t)(nx + i) * HIDDEN + kx + tx] = (__bf16)tile[tx][i];
    } else if (z < 11) {
        const int layer = z - 9;
        const float* W = conv_w + (size_t)layer * WSZ;
        __bf16* T = cw_nt + (size_t)layer * WSZ;
        for (int i = ty; i < 32; i += 8)
            T[(size_t)(kx + i) * HIDDEN + nx + tx] =
                (__bf16)W[(size_t)(kx + i) * HIDDEN + nx + tx];
    } else {
        if (blockIdx.x >= 4 || blockIdx.y != 0) return;
        const int zq = blockIdx.x;
        const int l = zq >> 1, branch = zq & 1;
        const float* cb = conv_b + (size_t)l * HIDDEN;
        const float* W  = (branch ? f1_w : f0_w) + (size_t)(l + 1) * WSZ;
        const int n = tt;
        float s = 0.f;
        #pragma unroll 4
        for (int k = 0; k < HIDDEN; ++k)
            s += cb[k] * W[(size_t)k * HIDDEN + n];
        q[(size_t)zq * HIDDEN + n] = s;
    }
}

__device__ __forceinline__ int block_incl_scan(int v, int* s, int t)
{
    s[t] = v; __syncthreads();
    #pragma unroll
    for (int off = 1; off < 256; off <<= 1) {
        int add = (t >= off) ? s[t - off] : 0;
        __syncthreads();
        s[t] += add;
        __syncthreads();
    }
    return s[t];
}

// K1b1 (R22): 196 blocks, one per BUCKET. Thread j scans column b of the
// 196x196 blkbucket matrix via a block scan -> per-block LOCAL base +
// bucket_size[b]. Replaces R8's single-block serial k1b (54us: one CU,
// 196-deep dependent global chain, 0.08% HBM).
__global__ __launch_bounds__(256) void k1b1_kernel(
    const int* __restrict__ blkbucket, int* __restrict__ blkbase,
    int* __restrict__ bucket_size)
{
    __shared__ int s[256];
    const int b = blockIdx.x;
    const int t = threadIdx.x;
    const int v = (t < EDGE_BLOCKS) ? blkbucket[t * 256 + b] : 0;
    const int incl = block_incl_scan(v, s, t);
    if (t < EDGE_BLOCKS) blkbase[t * 256 + b] = incl - v;   // local (in-bucket)
    if (t == 255) bucket_size[b] = incl;
}

// K1b2: 1 block: exclusive scan of bucket sizes -> bucket_base.
__global__ __launch_bounds__(256) void k1b2_kernel(
    const int* __restrict__ bucket_size, int* __restrict__ bucket_base)
{
    __shared__ int s[256];
    const int t = threadIdx.x;
    const int v = (t < NBUCKET) ? bucket_size[t] : 0;
    const int incl = block_incl_scan(v, s, t);
    if (t < NBUCKET) bucket_base[t] = incl - v;
}

// K1c: scatter edges into bucket_buf (packed src | (dst&255)<<16).
// LDS cursor per bucket; blocks write disjoint regions by construction.
__global__ __launch_bounds__(256) void k1c_kernel(
    const int* __restrict__ esrc, const int* __restrict__ edst,
    const int* __restrict__ blkbase, const int* __restrict__ bucket_base,
    unsigned int* __restrict__ bucket_buf)
{
    __shared__ int cur[256];
    const int blk = blockIdx.x;
    const int t = threadIdx.x;
    cur[t] = (t < NBUCKET) ? blkbase[blk * 256 + t] + bucket_base[t] : 0;
    __syncthreads();
    const int e0 = blk * 4096;
    #pragma unroll
    for (int j = 0; j < 16; ++j) {
        const int e = e0 + j * 256 + t;
        if (e < N_EDGES) {
            const int d = edst[e];
            const int p = atomicAdd(&cur[d >> 8], 1);
            bucket_buf[p] = (unsigned int)esrc[e] | ((unsigned int)(d & 255) << 16);
        }
    }
}

// K2a: per-bucket LDS node-count -> counts[] (true degree) + padded local
// exclusive scan. Bucket b == scan block b (256 nodes).
__global__ __launch_bounds__(256) void k2a_kernel(
    const unsigned int* __restrict__ bucket_buf,
    const int* __restrict__ bucket_base, const int* __restrict__ bucket_size,
    int* __restrict__ counts, int* __restrict__ offs_local,
    int* __restrict__ bsum)
{
    __shared__ int lcnt[256];
    __shared__ int s[256];
    const int b = blockIdx.x;
    const int t = threadIdx.x;
    lcnt[t] = 0;
    __syncthreads();
    const int bb = bucket_base[b], sz = bucket_size[b];
    for (int j = t; j < sz; j += 256)
        atomicAdd(&lcnt[bucket_buf[bb + j] >> 16], 1);
    __syncthreads();
    const int cnt = lcnt[t];
    counts[b * 256 + t] = cnt;
    const int pv = (cnt + 7) & ~7;
    const int incl = block_incl_scan(pv, s, t);
    offs_local[b * 256 + t] = incl - pv;
    if (t == 255) bsum[b] = incl;
}

__global__ __launch_bounds__(256) void scan2_kernel(
    const int* __restrict__ bsum, int* __restrict__ bbase)
{
    __shared__ int s[256];
    const int t = threadIdx.x;
    const int v = (t < SCAN_BLOCKS) ? bsum[t] : 0;
    int incl = block_incl_scan(v, s, t);
    bbase[t] = incl - v;
}

// K2b: finalize offs, fill u16 src_sorted via LDS cursors, sentinel pads.
// Output region per bucket is contiguous -> full-line write combining.
__global__ __launch_bounds__(256) void k2b_kernel(
    const unsigned int* __restrict__ bucket_buf,
    const int* __restrict__ bucket_base, const int* __restrict__ bucket_size,
    const int* __restrict__ offs_local, const int* __restrict__ bbase,
    int* __restrict__ offs, unsigned short* __restrict__ src_sorted)
{
    __shared__ int cur[256];
    const int b = blockIdx.x;
    const int t = threadIdx.x;
    const int off = offs_local[b * 256 + t] + bbase[b];
    offs[b * 256 + t] = off;
    cur[t] = off;
    __syncthreads();
    const int bb = bucket_base[b], sz = bucket_size[b];
    for (int j = t; j < sz; j += 256) {
        const unsigned int u = bucket_buf[bb + j];
        const int p = atomicAdd(&cur[u >> 16], 1);
        src_sorted[p] = (unsigned short)(u & 0xffffu);
    }
    __syncthreads();
    const int end = cur[t];
    const int pe  = off + ((end - off + 7) & ~7);
    for (int j = end; j < pe; ++j) src_sorted[j] = (unsigned short)N_NODES;
}

// ---------------------------------------------------------------------------
// XCD-sliced pull-mode segment sum, branch-free window-8 (R15).
// R22: u16 indices -> ONE 16B load per 8-edge window (was 2x 16B int4);
// halves the 8x-replicated src_sorted read stream (21 MB -> 10.5 MB).
// slice = blockIdx.x & 7 pins each 3.2MB column slice to one XCD L2.
// ---------------------------------------------------------------------------
template <bool COMPACT>
__global__ __launch_bounds__(256) void seg_slice_kernel(
    const __bf16* __restrict__ x0b,
    const unsigned short* __restrict__ srcs,
    const int* __restrict__ offs,      // PADDED offsets (multiples of 8)
    const int* __restrict__ nodelist,
    __bf16* __restrict__ out)
{
    const int slice = blockIdx.x & 7;
    const int chunk = blockIdx.x >> 3;
    const int t    = threadIdx.x;
    const int wave = t >> 6;
    const int lane = t & 63;
    const int g    = lane >> 2;      // 16 groups per wave
    const int li   = lane & 3;       // 4 lanes per dst row, 8 cols each
    const int rw   = chunk * 64 + wave * 16 + g;
    if (!COMPACT && rw >= N_NODES) return;

    const int d    = COMPACT ? nodelist[rw] : rw;
    const int beg  = offs[d];
    const int pdeg = offs[d + 1] - beg;   // multiple of 8

    const char* xb = (const char*)(x0b + (size_t)slice * SLICE_ELEMS);
    const uint32_t lioff = (uint32_t)li * 16u;
    const unsigned short* sp = srcs + beg;   // 16B-aligned (beg % 8 == 0)

    f32x2 a[4];
    #pragma unroll
    for (int j = 0; j < 4; ++j) a[j] = (f32x2){0.f, 0.f};

    uint4 j0;
    if (pdeg > 0) j0 = *(const uint4*)(sp);

    for (int base = 0; base < pdeg; base += 8) {
        const uint4 kv = j0;
        if (base + 8 < pdeg)              // prefetch next window's indices
            j0 = *(const uint4*)(sp + base + 8);
        const uint32_t i0 = kv.x & 0xffffu, i1 = kv.x >> 16;
        const uint32_t i2 = kv.y & 0xffffu, i3 = kv.y >> 16;
        const uint32_t i4 = kv.z & 0xffffu, i5 = kv.z >> 16;
        const uint32_t i6 = kv.w & 0xffffu, i7 = kv.w >> 16;
        const uint4 c0 = *(const uint4*)(xb + ((i0 << 6) + lioff));
        const uint4 c1 = *(const uint4*)(xb + ((i1 << 6) + lioff));
        const uint4 c2 = *(const uint4*)(xb + ((i2 << 6) + lioff));
        const uint4 c3 = *(const uint4*)(xb + ((i3 << 6) + lioff));
        const uint4 c4 = *(const uint4*)(xb + ((i4 << 6) + lioff));
        const uint4 c5 = *(const uint4*)(xb + ((i5 << 6) + lioff));
        const uint4 c6 = *(const uint4*)(xb + ((i6 << 6) + lioff));
        const uint4 c7 = *(const uint4*)(xb + ((i7 << 6) + lioff));
        acc8(c0, a); acc8(c1, a); acc8(c2, a); acc8(c3, a);
        acc8(c4, a); acc8(c5, a); acc8(c6, a); acc8(c7, a);
    }

    bf16x8 o;
    #pragma unroll
    for (int j = 0; j < 4; ++j) {
        o[2 * j]     = (__bf16)a[j].x;
        o[2 * j + 1] = (__bf16)a[j].y;
    }
    *(bf16x8*)(out + (size_t)rw * HIDDEN + (slice << 5) + li * 8) = o;
}

extern "C" void kernel_launch(void* const* d_in, const int* in_sizes, int n_in,
                              void* d_out, int out_size, void* d_ws, size_t ws_size,
                              hipStream_t stream)
{
    const float* x       = (const float*)d_in[0];
    const float* f0_w    = (const float*)d_in[1];
    const float* f0_b    = (const float*)d_in[2];
    const float* f1_w    = (const float*)d_in[3];
    const float* f1_b    = (const float*)d_in[4];
    const float* conv_w  = (const float*)d_in[5];
    const float* conv_b  = (const float*)d_in[6];
    const int*   edge_src = (const int*)d_in[7];
    const int*   edge_dst = (const int*)d_in[8];
    const int*   pos      = (const int*)d_in[9];
    float* out = (float*)d_out;

    const size_t buf = (size_t)N_NODES * HIDDEN;   // 12.8M elems

    char* p = (char*)d_ws;
    __bf16* bufA   = (__bf16*)p; p += buf * 2;                 // 25.6 MB (xb16 / S)
    __bf16* bufB   = (__bf16*)p; p += SLICE_ELEMS * 8 * 2;     // 25.6 MB+ (blocked x0)
    __bf16* s_lbl  = (__bf16*)p; p += (size_t)N_LABEL * HIDDEN * 2;  // 4 MB
    __bf16* wt_all = (__bf16*)p; p += (size_t)9 * WSZ * 2;
    __bf16* prod   = (__bf16*)p; p += (size_t)4 * WSZ * 2;
    __bf16* cw_nt  = (__bf16*)p; p += (size_t)2 * WSZ * 2;
    float*  qv     = (float*)p;  p += (size_t)4 * HIDDEN * 4;
    int* flags      = (int*)p;  p += NPAD * 4;                 // labeled-row bitmap
    int* counts     = (int*)p;  p += NPAD * 4;                 // true degree
    int* offs_local = (int*)p;  p += NPAD * 4;
    int* offs       = (int*)p;  p += NPAD * 4;                 // PADDED offsets
    int* bsum       = (int*)p;  p += 256 * 4;
    int* bbase      = (int*)p;  p += 256 * 4;
    int* blkbucket  = (int*)p;  p += (size_t)EDGE_BLOCKS * 256 * 4;  // 200 KB
    int* blkbase    = (int*)p;  p += (size_t)EDGE_BLOCKS * 256 * 4;  // 200 KB
    int* bucket_base= (int*)p;  p += 256 * 4;
    int* bucket_size= (int*)p;  p += 256 * 4;
    unsigned int* bucket_buf = (unsigned int*)p; p += (size_t)N_EDGES * 4;  // 3.2 MB
    unsigned short* src_sorted = (unsigned short*)p;
    p += (((size_t)(N_EDGES + 7 * NPAD) * 2 + 15) & ~(size_t)15);

    // ---- CSR build: deterministic two-level counting sort, 0 global atomics
    hipMemsetAsync(flags, 0, NPAD * sizeof(int), stream);
    wconv_kernel<<<dim3(8, 8, 114), dim3(32, 8), 0, stream>>>(
        f0_w, f1_w, conv_w, conv_b, wt_all, cw_nt, qv,
        edge_dst, pos, blkbucket, flags, bufB, x, bufA);
    k1b1_kernel<<<NBUCKET, 256, 0, stream>>>(blkbucket, blkbase, bucket_size);
    k1b2_kernel<<<1, 256, 0, stream>>>(bucket_size, bucket_base);
    k1c_kernel<<<EDGE_BLOCKS, 256, 0, stream>>>(
        edge_src, edge_dst, blkbase, bucket_base, bucket_buf);
    k2a_kernel<<<NBUCKET, 256, 0, stream>>>(
        bucket_buf, bucket_base, bucket_size, counts, offs_local, bsum);
    scan2_kernel<<<1, 256, 0, stream>>>(bsum, bbase);
    k2b_kernel<<<NBUCKET, 256, 0, stream>>>(
        bucket_buf, bucket_base, bucket_size, offs_local, bbase, offs, src_sorted);

    // all 4 products prod_t[z] = (Cw_l · F_{l+1})^T in ONE batched launch
    mfma_gemm<false, false, false, true, true><<<dim3(4, 2, 4), 256, 0, stream>>>(
        wt_all, cw_nt, nullptr, prod, nullptr, nullptr, HIDDEN);

    const dim3 fused_grid(782, 2, 2);   // z=0 full, z=1 label
    const dim3 lbl_grid(128, 2);

    __bf16* cur = bufA;              // S buffer (= xb16 at layer 0)
    __bf16* tmp = bufB;              // x0 buffer, COLUMN-BLOCKED layout

    for (int l = 0; l < N_LAYERS; ++l) {
        const float* B0 = f0_b + (size_t)l * HIDDEN;
        const float* B1 = f1_b + (size_t)l * HIDDEN;

        if (l == 0) {
            // x0 = xb16@F0_0+b0 (all, minus labeled) ∪ xb16@F1_0+b1 (labeled)
            mfma_gemm_fused<false><<<fused_grid, 256, 0, stream>>>(
                bufA, wt_all + 0 * WSZ, wt_all + 1 * WSZ,
                nullptr, nullptr, B0, B1, tmp, pos, counts, flags, N_NODES);
        } else {
            // x0 = S@(Cw·F0_l)+deg*q0+b0 ∪ S@(Cw·F1_l)+deg*q1+b1 (folded conv)
            const int z0 = (l - 1) * 2;
            mfma_gemm_fused<true><<<fused_grid, 256, 0, stream>>>(
                cur, prod + (size_t)z0 * WSZ, prod + (size_t)(z0 + 1) * WSZ,
                qv + (size_t)z0 * HIDDEN, qv + (size_t)(z0 + 1) * HIDDEN,
                B0, B1, tmp, pos, counts, flags, N_NODES);
        }

        if (l < N_LAYERS - 1) {
            // S = segment_sum(x0[src]) at ALL nodes (tmp -> cur), XCD-sliced
            seg_slice_kernel<false><<<8 * SEG_CHUNKS, 256, 0, stream>>>(
                tmp, src_sorted, offs, nullptr, cur);
        } else {
            // S only at labeled dst nodes (tmp -> s_lbl, compact pos order)
            seg_slice_kernel<true><<<8 * (N_LABEL / 64), 256, 0, stream>>>(
                tmp, src_sorted, offs, pos, s_lbl);
            // out[i] = S_lbl[i] @ Cw_2 + deg[pos[i]]*cb_2  -> d_out (fp32)
            mfma_gemm<false, true, true, false, false><<<lbl_grid, 256, 0, stream>>>(
                s_lbl, wt_all + (size_t)(2 * 3 + 2) * WSZ,
                conv_b + (size_t)2 * HIDDEN, out, pos, counts, N_LABEL);
        }
    }
}